// Round 1
// baseline (107.492 us; speedup 1.0000x reference)
//
#include <hip/hip_runtime.h>
#include <math.h>

// Problem constants (static shapes from setup_inputs; all arrays are float32)
#define B_   2
#define T_   8
#define R_   128
#define NP_  32768
#define F_   5
#define S_   32           // num_sample
#define NBT  (B_ * T_)    // 16
#define NROW (NBT * R_)   // 2048

__device__ __forceinline__ int mbcnt64(unsigned long long m) {
    return __builtin_amdgcn_mbcnt_hi((unsigned)(m >> 32),
           __builtin_amdgcn_mbcnt_lo((unsigned)m, 0u));
}

// ---------- kernel 1: vectorized AoS->SoA xy transpose + per-row constant prep ----------
// T = max{ x : sqrtf(x) <= radius } makes the scan predicate sqrt-free yet
// bit-identical (sqrtf monotone + correctly rounded).
__global__ __launch_bounds__(256) void xy_transpose_prep(
    const float* __restrict__ points,  // [bt, Np, 5]
    const float* __restrict__ rois,    // [bt, R, 9]
    float2* __restrict__ xy,           // [bt, Np]
    float4* __restrict__ rowc)         // [row] = {cx, cy, T, 0}
{
    const int j = blockIdx.x * blockDim.x + threadIdx.x;
    if (j < NBT * NP_ / 4) {
        const float4* src = (const float4*)points + (size_t)j * 5;
        const float4 a = src[0], b = src[1], c = src[2], d = src[3], e = src[4];
        float4* dst = (float4*)xy + (size_t)j * 2;
        dst[0] = make_float4(a.x, a.y, b.y, b.z);   // pts 4j, 4j+1
        dst[1] = make_float4(c.z, c.w, d.w, e.x);   // pts 4j+2, 4j+3
    }
    if (j < NROW) {
        const int row = j;                 // row = bt*R + r
        const int bt  = row / R_;
        const int t   = bt % T_;
        const float* roi = rois + (size_t)row * 9;
        const float cx = roi[0], cy = roi[1];
        const float hx = roi[3] * 0.5f, hy = roi[4] * 0.5f;
        const float vx = roi[7], vy = roi[8];
        const float speed  = sqrtf(vx * vx + vy * vy);
        const float base_g = 1.05f * (1.0f + speed);
        const float expo   = (float)t / 5.0f;
        const float gamma  = fminf((float)pow((double)base_g, (double)expo), 2.5f);
        const float radius = sqrtf(hx * hx + hy * hy) * gamma;   // same as passing rounds
        // ulp-walk: largest float T with sqrtf(T) <= radius
        unsigned ut = __float_as_uint(radius * radius);
        while (sqrtf(__uint_as_float(ut)) > radius) --ut;
        while (sqrtf(__uint_as_float(ut + 1u)) <= radius) ++ut;
        rowc[row] = make_float4(cx, cy, __uint_as_float(ut), 0.0f);
    }
}

// ---------- kernel 2 (fused): ordered scan with early exit + direct emission ----------
// One wave owns 2 rois and streams the whole bt's xy in index order with a
// 4-deep register prefetch. Hit indices (first 32 per roi, in point-index
// order — identical ballot/mbcnt logic to the verified segmented kernel) are
// staged in a tiny per-wave LDS buffer. As soon as both rois have >=32 hits
// the wave stops scanning (late hits were dropped by the base<S_ cap anyway,
// so the break point cannot change results). Gather + zero-fill happen here,
// killing the counts/hitidx round-trip and the third launch.

// PROC: test one float4 (= 2 consecutive points) against both rois.
#define PROC(qq, kk)                                                              \
    {                                                                             \
        const int idx0 = (it * 256 + (kk) * 64 + lane) * 2;                       \
        {   /* roi 0 — strict numpy rounding: mul, mul, add separate (no fma) */  \
            const float ax = __fsub_rn(qq.x, rc0.x), ay = __fsub_rn(qq.y, rc0.y); \
            const float bx = __fsub_rn(qq.z, rc0.x), by = __fsub_rn(qq.w, rc0.y); \
            const float d2a = __fadd_rn(__fmul_rn(ax, ax), __fmul_rn(ay, ay));    \
            const float d2b = __fadd_rn(__fmul_rn(bx, bx), __fmul_rn(by, by));    \
            const bool p0 = (d2a <= rc0.z), p1 = (d2b <= rc0.z);                  \
            const unsigned long long m0 = __ballot(p0), m1 = __ballot(p1);        \
            if (m0 | m1) {                                                        \
                const int base = sel0 + mbcnt64(m0) + mbcnt64(m1);                \
                if (p0 && base < S_) hitbuf[w][0][base] = (unsigned short)idx0;   \
                if (p1) { const int s2 = base + (p0 ? 1 : 0);                     \
                          if (s2 < S_) hitbuf[w][0][s2] = (unsigned short)(idx0 + 1); } \
                sel0 += __popcll(m0) + __popcll(m1);                              \
            }                                                                     \
        }                                                                         \
        {   /* roi 1 — re-uses the same register data */                          \
            const float ax = __fsub_rn(qq.x, rc1.x), ay = __fsub_rn(qq.y, rc1.y); \
            const float bx = __fsub_rn(qq.z, rc1.x), by = __fsub_rn(qq.w, rc1.y); \
            const float d2a = __fadd_rn(__fmul_rn(ax, ax), __fmul_rn(ay, ay));    \
            const float d2b = __fadd_rn(__fmul_rn(bx, bx), __fmul_rn(by, by));    \
            const bool p0 = (d2a <= rc1.z), p1 = (d2b <= rc1.z);                  \
            const unsigned long long m0 = __ballot(p0), m1 = __ballot(p1);        \
            if (m0 | m1) {                                                        \
                const int base = sel1 + mbcnt64(m0) + mbcnt64(m1);                \
                if (p0 && base < S_) hitbuf[w][1][base] = (unsigned short)idx0;   \
                if (p1) { const int s2 = base + (p0 ? 1 : 0);                     \
                          if (s2 < S_) hitbuf[w][1][s2] = (unsigned short)(idx0 + 1); } \
                sel1 += __popcll(m0) + __popcll(m1);                              \
            }                                                                     \
        }                                                                         \
    }

__global__ __launch_bounds__(256) void fused_scan_emit(
    const float2* __restrict__ xy,     // [bt, Np]
    const float4* __restrict__ rowc,   // [row] = {cx, cy, T, 0}
    const float* __restrict__ points,  // [bt, Np, 5]
    float* __restrict__ out)           // [B, R, T*S, 5]
{
    __shared__ unsigned short hitbuf[4][2][S_];   // 512 B: per wave, per roi
    const int w    = threadIdx.x >> 6;
    const int lane = threadIdx.x & 63;
    const int row0 = blockIdx.x * 8 + w * 2;      // 2 rois per wave, 8 per block
    const int row1 = row0 + 1;
    const int bt   = row0 / R_;                   // same bt for the whole block
    const float4 rc0 = rowc[row0], rc1 = rowc[row1];

    // coalesced stream: lane reads float4 = 2 points; 4 chunks (512 pts) per iter
    const float4* src = (const float4*)(xy + (size_t)bt * NP_) + lane;
    int sel0 = 0, sel1 = 0;
    float4 q0 = src[0], q1 = src[64], q2 = src[128], q3 = src[192];
    src += 256;
    int it = 0;
    for (; it < 63; ++it) {
        const float4 t0 = src[0], t1 = src[64], t2 = src[128], t3 = src[192];
        src += 256;
        PROC(q0, 0) PROC(q1, 1) PROC(q2, 2) PROC(q3, 3)
        q0 = t0; q1 = t1; q2 = t2; q3 = t3;
        if (sel0 >= S_ && sel1 >= S_) break;      // sel0/sel1 wave-uniform
    }
    if (it == 63) { PROC(q0, 0) PROC(q1, 1) PROC(q2, 2) PROC(q3, 3) }

    __syncthreads();   // orders hitbuf writes before reads (also reconverges waves)

    // emission: lanes 0..31 -> roi0 slots, lanes 32..63 -> roi1 slots
    const int half  = lane >> 5;
    const int s     = lane & 31;
    const int row   = half ? row1 : row0;
    const int sel   = half ? sel1 : sel0;
    const int total = sel < S_ ? sel : S_;
    const int r = row % R_;
    const int t = bt % T_;
    const int b = bt / T_;
    float* o = out + ((((size_t)b * R_ + r) * T_ + t) * S_ + s) * (size_t)F_;
    if (s < total) {
        const int pi = hitbuf[w][half][s];
        const float* p = points + ((size_t)bt * NP_ + pi) * F_;
        o[0] = p[0]; o[1] = p[1]; o[2] = p[2]; o[3] = p[3]; o[4] = p[4];
    } else {
        o[0] = 0.0f; o[1] = 0.0f; o[2] = 0.0f; o[3] = 0.0f; o[4] = 0.0f;
    }
}

extern "C" void kernel_launch(void* const* d_in, const int* in_sizes, int n_in,
                              void* d_out, int out_size, void* d_ws, size_t ws_size,
                              hipStream_t stream) {
    const float* points = (const float*)d_in[0];
    const float* rois   = (const float*)d_in[1];
    float* out = (float*)d_out;

    // workspace layout (~4.2 MB): xy transpose + per-row constants
    char* ws = (char*)d_ws;
    float2* xy   = (float2*)ws;                 // 4,194,304 B
    float4* rowc = (float4*)(ws + 4194304);     //    32,768 B

    // 1) vectorized transpose + per-row constants (fused)
    xy_transpose_prep<<<(NBT * NP_ / 4 + 255) / 256, 256, 0, stream>>>(points, rois, xy, rowc);

    // 2) fused ordered scan (early exit) + gather + zero-fill: 1 wave per 2 rois
    fused_scan_emit<<<NROW / 8, 256, 0, stream>>>(xy, rowc, points, out);
}

// Round 2
// 82.533 us; speedup vs baseline: 1.3024x; 1.3024x over previous
//
#include <hip/hip_runtime.h>
#include <math.h>

// Problem constants (static shapes from setup_inputs; all arrays are float32)
#define B_   2
#define T_   8
#define R_   128
#define NP_  32768
#define F_   5
#define S_   32           // num_sample
#define NBT  (B_ * T_)    // 16
#define NROW (NBT * R_)   // 2048
#define WV_  8            // waves per block = segments per roi-pair
#define SEGPTS (NP_ / WV_)   // 4096 points per wave-segment
#define NIT  (SEGPTS / 512)  // 8 iterations (512 pts per iteration)

__device__ __forceinline__ int mbcnt64(unsigned long long m) {
    return __builtin_amdgcn_mbcnt_hi((unsigned)(m >> 32),
           __builtin_amdgcn_mbcnt_lo((unsigned)m, 0u));
}

// ---------- kernel 1: vectorized AoS->SoA xy transpose + per-row constant prep ----------
// T = max{ x : sqrtf(x) <= radius } makes the scan predicate sqrt-free yet
// bit-identical (sqrtf monotone + correctly rounded).
__global__ __launch_bounds__(256) void xy_transpose_prep(
    const float* __restrict__ points,  // [bt, Np, 5]
    const float* __restrict__ rois,    // [bt, R, 9]
    float2* __restrict__ xy,           // [bt, Np]
    float4* __restrict__ rowc)         // [row] = {cx, cy, T, 0}
{
    const int j = blockIdx.x * blockDim.x + threadIdx.x;
    if (j < NBT * NP_ / 4) {
        const float4* src = (const float4*)points + (size_t)j * 5;
        const float4 a = src[0], b = src[1], c = src[2], d = src[3], e = src[4];
        float4* dst = (float4*)xy + (size_t)j * 2;
        dst[0] = make_float4(a.x, a.y, b.y, b.z);   // pts 4j, 4j+1
        dst[1] = make_float4(c.z, c.w, d.w, e.x);   // pts 4j+2, 4j+3
    }
    if (j < NROW) {
        const int row = j;                 // row = bt*R + r
        const int bt  = row / R_;
        const int t   = bt % T_;
        const float* roi = rois + (size_t)row * 9;
        const float cx = roi[0], cy = roi[1];
        const float hx = roi[3] * 0.5f, hy = roi[4] * 0.5f;
        const float vx = roi[7], vy = roi[8];
        const float speed  = sqrtf(vx * vx + vy * vy);
        const float base_g = 1.05f * (1.0f + speed);
        const float expo   = (float)t / 5.0f;
        const float gamma  = fminf((float)pow((double)base_g, (double)expo), 2.5f);
        const float radius = sqrtf(hx * hx + hy * hy) * gamma;   // same as passing rounds
        // ulp-walk: largest float T with sqrtf(T) <= radius
        unsigned ut = __float_as_uint(radius * radius);
        while (sqrtf(__uint_as_float(ut)) > radius) --ut;
        while (sqrtf(__uint_as_float(ut + 1u)) <= radius) ++ut;
        rowc[row] = make_float4(cx, cy, __uint_as_float(ut), 0.0f);
    }
}

// ---------- kernel 2 (fused, segment-parallel): scan + in-LDS merge + emission ----------
// One block (512 thr = 8 waves) owns one roi-PAIR. Wave w scans segment w
// (4096 points, index order) for both rois with the verified ballot/mbcnt
// ordered-insertion logic, stopping early once its local lists are full.
// Per-segment lists (<=32 each) merge via an 8-count prefix in LDS; since
// segments and in-segment hits are index-ordered, concatenation order ==
// global index order, and a segment with >32 local hits clamps safely (the
// global first-32 can never need more than 32 hits of an earlier segment).
// 1024 blocks x 8 waves = 32 waves/CU: latency hidden by TLP, chain is 8 iters.

// PROC: test one float4 (= 2 consecutive points) against both rois.
#define PROC(qq, kk)                                                              \
    {                                                                             \
        const int idx0 = segbase + (it * 256 + (kk) * 64 + lane) * 2;             \
        {   /* roi 0 — strict numpy rounding: mul, mul, add separate (no fma) */  \
            const float ax = __fsub_rn(qq.x, rc0.x), ay = __fsub_rn(qq.y, rc0.y); \
            const float bx = __fsub_rn(qq.z, rc0.x), by = __fsub_rn(qq.w, rc0.y); \
            const float d2a = __fadd_rn(__fmul_rn(ax, ax), __fmul_rn(ay, ay));    \
            const float d2b = __fadd_rn(__fmul_rn(bx, bx), __fmul_rn(by, by));    \
            const bool p0 = (d2a <= rc0.z), p1 = (d2b <= rc0.z);                  \
            const unsigned long long m0 = __ballot(p0), m1 = __ballot(p1);        \
            if (m0 | m1) {                                                        \
                const int base = sel0 + mbcnt64(m0) + mbcnt64(m1);                \
                if (p0 && base < S_) hitbuf[w][0][base] = (unsigned short)idx0;   \
                if (p1) { const int s2 = base + (p0 ? 1 : 0);                     \
                          if (s2 < S_) hitbuf[w][0][s2] = (unsigned short)(idx0 + 1); } \
                sel0 += __popcll(m0) + __popcll(m1);                              \
            }                                                                     \
        }                                                                         \
        {   /* roi 1 — re-uses the same register data */                          \
            const float ax = __fsub_rn(qq.x, rc1.x), ay = __fsub_rn(qq.y, rc1.y); \
            const float bx = __fsub_rn(qq.z, rc1.x), by = __fsub_rn(qq.w, rc1.y); \
            const float d2a = __fadd_rn(__fmul_rn(ax, ax), __fmul_rn(ay, ay));    \
            const float d2b = __fadd_rn(__fmul_rn(bx, bx), __fmul_rn(by, by));    \
            const bool p0 = (d2a <= rc1.z), p1 = (d2b <= rc1.z);                  \
            const unsigned long long m0 = __ballot(p0), m1 = __ballot(p1);        \
            if (m0 | m1) {                                                        \
                const int base = sel1 + mbcnt64(m0) + mbcnt64(m1);                \
                if (p0 && base < S_) hitbuf[w][1][base] = (unsigned short)idx0;   \
                if (p1) { const int s2 = base + (p0 ? 1 : 0);                     \
                          if (s2 < S_) hitbuf[w][1][s2] = (unsigned short)(idx0 + 1); } \
                sel1 += __popcll(m0) + __popcll(m1);                              \
            }                                                                     \
        }                                                                         \
    }

__global__ __launch_bounds__(512) void fused_scan_emit(
    const float2* __restrict__ xy,     // [bt, Np]
    const float4* __restrict__ rowc,   // [row] = {cx, cy, T, 0}
    const float* __restrict__ points,  // [bt, Np, 5]
    float* __restrict__ out)           // [B, R, T*S, 5]
{
    __shared__ unsigned short hitbuf[WV_][2][S_];   // 1 KB
    __shared__ int cnt[WV_][2];
    const int w    = threadIdx.x >> 6;
    const int lane = threadIdx.x & 63;
    const int row0 = blockIdx.x * 2;               // one roi-pair per block
    const int row1 = row0 + 1;
    const int bt   = row0 / R_;
    const float4 rc0 = rowc[row0], rc1 = rowc[row1];
    const int segbase = w * SEGPTS;                // this wave's point range

    // coalesced stream: lane reads float4 = 2 points; 4 chunks (512 pts) per iter
    const float4* src = (const float4*)(xy + (size_t)bt * NP_) + (segbase >> 1) + lane;
    int sel0 = 0, sel1 = 0;
    float4 q0 = src[0], q1 = src[64], q2 = src[128], q3 = src[192];
    src += 256;
    int it = 0;
    for (; it < NIT - 1; ++it) {
        const float4 t0 = src[0], t1 = src[64], t2 = src[128], t3 = src[192];
        src += 256;
        PROC(q0, 0) PROC(q1, 1) PROC(q2, 2) PROC(q3, 3)
        q0 = t0; q1 = t1; q2 = t2; q3 = t3;
        if (sel0 >= S_ && sel1 >= S_) break;       // local lists full (wave-uniform)
    }
    if (it == NIT - 1) { PROC(q0, 0) PROC(q1, 1) PROC(q2, 2) PROC(q3, 3) }

    if (lane == 0) {
        cnt[w][0] = (sel0 < S_) ? sel0 : S_;
        cnt[w][1] = (sel1 < S_) ? sel1 : S_;
    }
    __syncthreads();   // all segment lists + counts visible

    // emission: 64 output slots per block (2 rois x 32); first wave handles them
    if (threadIdx.x < 64) {
        const int half = lane >> 5;                // 0 -> roi0, 1 -> roi1
        const int s    = lane & 31;
        int seg = -1, local = 0, acc = 0;
        #pragma unroll
        for (int g = 0; g < WV_; ++g) {
            const int na = acc + cnt[g][half];
            if (seg < 0 && s < na) { seg = g; local = s - acc; }
            acc = na;
        }
        const int row = half ? row1 : row0;
        const int r = row % R_;
        const int t = bt % T_;
        const int b = bt / T_;
        float* o = out + ((((size_t)b * R_ + r) * T_ + t) * S_ + s) * (size_t)F_;
        if (seg >= 0) {
            const int pi = hitbuf[seg][half][local];
            const float* p = points + ((size_t)bt * NP_ + pi) * F_;
            o[0] = p[0]; o[1] = p[1]; o[2] = p[2]; o[3] = p[3]; o[4] = p[4];
        } else {
            o[0] = 0.0f; o[1] = 0.0f; o[2] = 0.0f; o[3] = 0.0f; o[4] = 0.0f;
        }
    }
}

extern "C" void kernel_launch(void* const* d_in, const int* in_sizes, int n_in,
                              void* d_out, int out_size, void* d_ws, size_t ws_size,
                              hipStream_t stream) {
    const float* points = (const float*)d_in[0];
    const float* rois   = (const float*)d_in[1];
    float* out = (float*)d_out;

    // workspace layout (~4.2 MB): xy transpose + per-row constants
    char* ws = (char*)d_ws;
    float2* xy   = (float2*)ws;                 // 4,194,304 B
    float4* rowc = (float4*)(ws + 4194304);     //    32,768 B

    // 1) vectorized transpose + per-row constants (fused)
    xy_transpose_prep<<<(NBT * NP_ / 4 + 255) / 256, 256, 0, stream>>>(points, rois, xy, rowc);

    // 2) fused segment-parallel scan + in-LDS merge + emission: 1 block per roi-pair
    fused_scan_emit<<<NROW / 2, 512, 0, stream>>>(xy, rowc, points, out);
}